// Round 7
// baseline (584.098 us; speedup 1.0000x reference)
//
#include <hip/hip_runtime.h>

#define NN 50000
#define NE 1600000
#define DD 128
#define NL 4
#define NG 512
#define NT 196      // ceil(NN/256)
#define NREP 8      // degree-counter replicas, one per physical XCD (XCC_ID)
#define RSTRIDE 50176  // NT*256, padded node stride for replica arrays
#define NBE 1563    // ceil(NE/4/256)

typedef __attribute__((ext_vector_type(8))) short short8;
typedef __attribute__((ext_vector_type(4))) float floatx4;

__device__ __forceinline__ unsigned short f2bf(float f) {
    unsigned int u = __float_as_uint(f);
    u += 0x7fffu + ((u >> 16) & 1u);
    return (unsigned short)(u >> 16);
}
__device__ __forceinline__ float bf2f(unsigned short u) {
    return __uint_as_float(((unsigned int)u) << 16);
}
__device__ __forceinline__ unsigned int get_xcd() {
    unsigned int xcc;
    asm volatile("s_getreg_b32 %0, hwreg(HW_REG_XCC_ID)" : "=s"(xcc));
    return xcc & (NREP - 1);
}

// ---------- fp32 -> bf16 convert (layer-0 input) ----------
__global__ __launch_bounds__(256) void cvt_kernel(const float* __restrict__ x,
                                                  unsigned short* __restrict__ xbf) {
    int idx = blockIdx.x * 256 + threadIdx.x;  // one float4 per thread
    float4 f = ((const float4*)x)[idx];
    ushort4 o;
    o.x = f2bf(f.x); o.y = f2bf(f.y); o.z = f2bf(f.z); o.w = f2bf(f.w);
    ((ushort4*)xbf)[idx] = o;
}

// ---------- CSR build ----------
// pos_kernel: replicas indexed by PHYSICAL XCD (s_getreg HW_REG_XCC_ID), atomics at
// workgroup scope so the RMW executes in the local XCD L2 instead of memory-side
// (device-scope atomics cost a fixed ~32B fabric round trip each — R6 counters).
// Replica r is only ever touched from XCD r => single-L2 serialization is atomic.
// The XCD id is packed into pos bits 28..31 for fill_kernel.
__global__ __launch_bounds__(256) void pos_kernel(const int* __restrict__ dst,
                                                  int* __restrict__ degr,
                                                  int* __restrict__ pos) {
    int t = blockIdx.x * 256 + threadIdx.x;  // [0, NE/4)
    if (t >= NE / 4) return;
    unsigned int xcc = get_xcd();
    int* d0 = degr + xcc * RSTRIDE;
    int tag = (int)(xcc << 28);
    int4 d = ((const int4*)dst)[t];
    int4 p;
    p.x = __hip_atomic_fetch_add(&d0[d.x], 1, __ATOMIC_RELAXED, __HIP_MEMORY_SCOPE_WORKGROUP) | tag;
    p.y = __hip_atomic_fetch_add(&d0[d.y], 1, __ATOMIC_RELAXED, __HIP_MEMORY_SCOPE_WORKGROUP) | tag;
    p.z = __hip_atomic_fetch_add(&d0[d.z], 1, __ATOMIC_RELAXED, __HIP_MEMORY_SCOPE_WORKGROUP) | tag;
    p.w = __hip_atomic_fetch_add(&d0[d.w], 1, __ATOMIC_RELAXED, __HIP_MEMORY_SCOPE_WORKGROUP) | tag;
    ((int4*)pos)[t] = p;
}

// merge: per node, exclusive prefix over the 8 replica counts (in place -> roff),
// total -> deg
__global__ __launch_bounds__(256) void merge_kernel(int* __restrict__ degr,
                                                    int* __restrict__ deg) {
    int i = blockIdx.x * 256 + threadIdx.x;
    if (i >= NN) return;
    int s = 0;
#pragma unroll
    for (int r = 0; r < NREP; r++) {
        int t = degr[r * RSTRIDE + i];
        degr[r * RSTRIDE + i] = s;
        s += t;
    }
    deg[i] = s;
}

// ---------- parallel exclusive scan of deg -> rowptr (3 kernels, full-chip) ----------
__global__ __launch_bounds__(256) void tilesum_kernel(const int* __restrict__ deg,
                                                      int* __restrict__ tilesum) {
    int i = blockIdx.x * 256 + threadIdx.x;
    int v = (i < NN) ? deg[i] : 0;
    __shared__ int s[256];
    s[threadIdx.x] = v;
    __syncthreads();
    for (int off = 128; off > 0; off >>= 1) {
        if (threadIdx.x < off) s[threadIdx.x] += s[threadIdx.x + off];
        __syncthreads();
    }
    if (threadIdx.x == 0) tilesum[blockIdx.x] = s[0];
}

__global__ __launch_bounds__(256) void tilescan_kernel(const int* __restrict__ tilesum,
                                                       int* __restrict__ tileoff,
                                                       int* __restrict__ rowptr) {
    int t = threadIdx.x;
    __shared__ int s[256];
    int v = (t < NT) ? tilesum[t] : 0;
    s[t] = v;
    __syncthreads();
    for (int off = 1; off < 256; off <<= 1) {
        int u = (t >= off) ? s[t - off] : 0;
        __syncthreads();
        s[t] += u;
        __syncthreads();
    }
    if (t < NT) tileoff[t] = s[t] - v;   // exclusive tile offset
    if (t == NT - 1) rowptr[NN] = s[t];  // grand total
}

__global__ __launch_bounds__(256) void rowptr_kernel(const int* __restrict__ deg,
                                                     const int* __restrict__ tileoff,
                                                     int* __restrict__ rowptr) {
    int i = blockIdx.x * 256 + threadIdx.x;
    int t = threadIdx.x;
    int v = (i < NN) ? deg[i] : 0;
    __shared__ int s[256];
    s[t] = v;
    __syncthreads();
    for (int off = 1; off < 256; off <<= 1) {
        int u = (t >= off) ? s[t - off] : 0;
        __syncthreads();
        s[t] += u;
        __syncthreads();
    }
    if (i < NN) rowptr[i] = tileoff[blockIdx.x] + s[t] - v;
}

// atomic-free scatter: col[rowptr[d] + roff[rep][d] + pos[e]] = src[e]
// rep comes from pos bits 28..31 (the XCD that counted this edge).
__global__ __launch_bounds__(256) void fill_kernel(const int* __restrict__ src,
                                                   const int* __restrict__ dst,
                                                   const int* __restrict__ pos,
                                                   const int* __restrict__ rowptr,
                                                   const int* __restrict__ roff,
                                                   int* __restrict__ col) {
    int t = blockIdx.x * 256 + threadIdx.x;  // [0, NE/4)
    if (t >= NE / 4) return;
    int4 d = ((const int4*)dst)[t];
    int4 p = ((const int4*)pos)[t];
    int4 s = ((const int4*)src)[t];
    col[rowptr[d.x] + roff[((unsigned)p.x >> 28) * RSTRIDE + d.x] + (p.x & 0x0FFFFFFF)] = s.x;
    col[rowptr[d.y] + roff[((unsigned)p.y >> 28) * RSTRIDE + d.y] + (p.y & 0x0FFFFFFF)] = s.y;
    col[rowptr[d.z] + roff[((unsigned)p.z >> 28) * RSTRIDE + d.z] + (p.z & 0x0FFFFFFF)] = s.z;
    col[rowptr[d.w] + roff[((unsigned)p.w >> 28) * RSTRIDE + d.w] + (p.w & 0x0FFFFFFF)] = s.w;
}

// ---------- weight prep: fp32 [l][k][n] -> bf16 transposed [l][n][k] ----------
__global__ __launch_bounds__(256) void prep_kernel(const float* __restrict__ Ws1,
                                                   const float* __restrict__ Ws2,
                                                   unsigned short* __restrict__ W1T,
                                                   unsigned short* __restrict__ W2T) {
    int idx = blockIdx.x * 256 + threadIdx.x;  // [0, NL*DD*DD)
    int l = idx >> 14;
    int rem = idx & 16383;
    int k = rem >> 7;
    int n = rem & 127;
    int o = (l << 14) + (n << 7) + k;
    W1T[o] = f2bf(Ws1[idx]);
    W2T[o] = f2bf(Ws2[idx]);
}

// ---------- aggregation: hpre[i] = x[i] + sum_{j in N(i)} x[j], bf16 in/out ----------
// Standalone (NOT fused with MLP — R5: fusing cost 2.4x fetch rate via occupancy).
// 16 lanes/node, uint4 (8 bf16) per lane; fp32 accum; x8 edge unroll => 128 B/lane
// in flight for latency hiding. Row = 16 uint4s, so uint4 index = node*16+lane.
__global__ __launch_bounds__(256) void agg_kernel(const unsigned short* __restrict__ xbf,
                                                  const int* __restrict__ rowptr,
                                                  const int* __restrict__ col,
                                                  unsigned short* __restrict__ hpre) {
    int g = threadIdx.x >> 4;   // 16 node-groups per block
    int lane = threadIdx.x & 15;
    int node = blockIdx.x * 16 + g;  // NN = 3125*16 exactly
    const uint4* base = (const uint4*)xbf;
    float a[8];
    {
        uint4 v = base[node * 16 + lane];
        a[0] = __uint_as_float(v.x << 16); a[1] = __uint_as_float(v.x & 0xFFFF0000u);
        a[2] = __uint_as_float(v.y << 16); a[3] = __uint_as_float(v.y & 0xFFFF0000u);
        a[4] = __uint_as_float(v.z << 16); a[5] = __uint_as_float(v.z & 0xFFFF0000u);
        a[6] = __uint_as_float(v.w << 16); a[7] = __uint_as_float(v.w & 0xFFFF0000u);
    }
    int s = rowptr[node], e = rowptr[node + 1];
    int i = s;
    for (; i + 8 <= e; i += 8) {
        uint4 v0 = base[col[i] * 16 + lane];
        uint4 v1 = base[col[i + 1] * 16 + lane];
        uint4 v2 = base[col[i + 2] * 16 + lane];
        uint4 v3 = base[col[i + 3] * 16 + lane];
        uint4 v4 = base[col[i + 4] * 16 + lane];
        uint4 v5 = base[col[i + 5] * 16 + lane];
        uint4 v6 = base[col[i + 6] * 16 + lane];
        uint4 v7 = base[col[i + 7] * 16 + lane];
#define ACC(V)                                                            \
        a[0] += __uint_as_float(V.x << 16); a[1] += __uint_as_float(V.x & 0xFFFF0000u); \
        a[2] += __uint_as_float(V.y << 16); a[3] += __uint_as_float(V.y & 0xFFFF0000u); \
        a[4] += __uint_as_float(V.z << 16); a[5] += __uint_as_float(V.z & 0xFFFF0000u); \
        a[6] += __uint_as_float(V.w << 16); a[7] += __uint_as_float(V.w & 0xFFFF0000u)
        ACC(v0); ACC(v1); ACC(v2); ACC(v3); ACC(v4); ACC(v5); ACC(v6); ACC(v7);
    }
    for (; i < e; i++) {
        uint4 v = base[col[i] * 16 + lane];
        ACC(v);
    }
#undef ACC
    uint4 o;
    o.x = (unsigned int)f2bf(a[0]) | ((unsigned int)f2bf(a[1]) << 16);
    o.y = (unsigned int)f2bf(a[2]) | ((unsigned int)f2bf(a[3]) << 16);
    o.z = (unsigned int)f2bf(a[4]) | ((unsigned int)f2bf(a[5]) << 16);
    o.w = (unsigned int)f2bf(a[6]) | ((unsigned int)f2bf(a[7]) << 16);
    ((uint4*)hpre)[node * 16 + lane] = o;
}

// ---------- fused MLP: out = relu(A@W1+b1)@W2 + b2 (bf16 in/out, fp32 accum) ----------
// 64 rows/block, 4 waves, wave w owns rows [16w,16w+16); 8 n-tiles per wave.
__global__ __launch_bounds__(256) void mlp_kernel(const unsigned short* __restrict__ A,
                                                  const unsigned short* __restrict__ W1T,
                                                  const float* __restrict__ b1,
                                                  const unsigned short* __restrict__ W2T,
                                                  const float* __restrict__ b2,
                                                  unsigned short* __restrict__ out) {
    __shared__ unsigned short Hs[64][136];  // +8 pad
    int tid = threadIdx.x;
    int w = tid >> 6;
    int lane = tid & 63;
    int quad = lane >> 4;
    int li = lane & 15;
    int row0 = blockIdx.x * 64;
    int arow = row0 + 16 * w + li;
    bool avalid = arow < NN;
    const unsigned short* arp = A + (size_t)arow * DD;

    floatx4 acc[8];
#pragma unroll
    for (int tn = 0; tn < 8; tn++) acc[tn] = (floatx4){0.f, 0.f, 0.f, 0.f};

#pragma unroll
    for (int kk = 0; kk < 4; kk++) {
        int k0 = kk * 32 + quad * 8;
        short8 af = avalid ? *(const short8*)(arp + k0)
                           : (short8){0, 0, 0, 0, 0, 0, 0, 0};
#pragma unroll
        for (int tn = 0; tn < 8; tn++) {
            short8 bf = *(const short8*)(W1T + ((tn * 16 + li) << 7) + k0);
            acc[tn] = __builtin_amdgcn_mfma_f32_16x16x32_bf16(af, bf, acc[tn], 0, 0, 0);
        }
    }
    // epilogue A: relu(acc + b1) -> Hs (bf16, row-major for stage-B A-fragments)
#pragma unroll
    for (int tn = 0; tn < 8; tn++) {
        float bias = b1[tn * 16 + li];
#pragma unroll
        for (int r = 0; r < 4; r++) {
            float v = acc[tn][r] + bias;
            v = fmaxf(v, 0.f);
            Hs[16 * w + quad * 4 + r][tn * 16 + li] = f2bf(v);
        }
    }
    __syncthreads();

#pragma unroll
    for (int tn = 0; tn < 8; tn++) acc[tn] = (floatx4){0.f, 0.f, 0.f, 0.f};
#pragma unroll
    for (int kk = 0; kk < 4; kk++) {
        int k0 = kk * 32 + quad * 8;
        short8 af = *(const short8*)&Hs[16 * w + li][k0];
#pragma unroll
        for (int tn = 0; tn < 8; tn++) {
            short8 bf = *(const short8*)(W2T + ((tn * 16 + li) << 7) + k0);
            acc[tn] = __builtin_amdgcn_mfma_f32_16x16x32_bf16(af, bf, acc[tn], 0, 0, 0);
        }
    }
#pragma unroll
    for (int tn = 0; tn < 8; tn++) {
        float bias = b2[tn * 16 + li];
#pragma unroll
        for (int r = 0; r < 4; r++) {
            int grow = row0 + 16 * w + quad * 4 + r;
            if (grow < NN) out[(size_t)grow * DD + tn * 16 + li] = f2bf(acc[tn][r] + bias);
        }
    }
}

// ---------- global add pool: batch sorted -> per-graph contiguous range ----------
__global__ __launch_bounds__(128) void pool_kernel(const unsigned short* __restrict__ x,
                                                   const int* __restrict__ batch,
                                                   float* __restrict__ out) {
    int g = blockIdx.x;
    int lo = 0, hi = NN;
    while (lo < hi) { int mid = (lo + hi) >> 1; if (batch[mid] < g) lo = mid + 1; else hi = mid; }
    int s = lo;
    hi = NN;
    while (lo < hi) { int mid = (lo + hi) >> 1; if (batch[mid] < g + 1) lo = mid + 1; else hi = mid; }
    int e = lo;
    int d = threadIdx.x;
    float acc = 0.f;
    for (int i = s; i < e; i++) acc += bf2f(x[(size_t)i * DD + d]);
    out[g * DD + d] = acc;
}

extern "C" void kernel_launch(void* const* d_in, const int* in_sizes, int n_in,
                              void* d_out, int out_size, void* d_ws, size_t ws_size,
                              hipStream_t stream) {
    const float* x0 = (const float*)d_in[0];
    const int* edge = (const int*)d_in[1];
    const int* batch = (const int*)d_in[2];
    const float* Ws1 = (const float*)d_in[3];
    const float* bs1 = (const float*)d_in[4];
    const float* Ws2 = (const float*)d_in[5];
    const float* bs2 = (const float*)d_in[6];
    float* out = (float*)d_out;
    const int* src = edge;
    const int* dst = edge + NE;

    char* ws = (char*)d_ws;
    size_t off = 0;
    auto alloc = [&](size_t bytes) {
        void* p = ws + off;
        off += (bytes + 255) & ~(size_t)255;
        return p;
    };
    unsigned short* x0bf = (unsigned short*)alloc((size_t)NN * DD * 2);
    unsigned short* xA = (unsigned short*)alloc((size_t)NN * DD * 2);
    unsigned short* xB = (unsigned short*)alloc((size_t)NN * DD * 2);
    unsigned short* hpre = (unsigned short*)alloc((size_t)NN * DD * 2);
    int* col = (int*)alloc((size_t)NE * 4);
    int* pos = (int*)alloc((size_t)NE * 4);
    int* rowptr = (int*)alloc((size_t)(NN + 1) * 4);
    int* deg = (int*)alloc((size_t)(NN + 1) * 4);
    int* degr = (int*)alloc((size_t)NREP * RSTRIDE * 4);  // counters, then roff in-place
    int* tilesum = (int*)alloc((size_t)NT * 4);
    int* tileoff = (int*)alloc((size_t)NT * 4);
    unsigned short* W1T = (unsigned short*)alloc((size_t)NL * DD * DD * 2);
    unsigned short* W2T = (unsigned short*)alloc((size_t)NL * DD * DD * 2);

    hipMemsetAsync(degr, 0, (size_t)NREP * RSTRIDE * 4, stream);

    cvt_kernel<<<(NN * DD / 4) / 256, 256, 0, stream>>>(x0, x0bf);
    pos_kernel<<<NBE, 256, 0, stream>>>(dst, degr, pos);
    merge_kernel<<<NT, 256, 0, stream>>>(degr, deg);
    tilesum_kernel<<<NT, 256, 0, stream>>>(deg, tilesum);
    tilescan_kernel<<<1, 256, 0, stream>>>(tilesum, tileoff, rowptr);
    rowptr_kernel<<<NT, 256, 0, stream>>>(deg, tileoff, rowptr);
    fill_kernel<<<NBE, 256, 0, stream>>>(src, dst, pos, rowptr, degr, col);
    prep_kernel<<<(NL * DD * DD) / 256, 256, 0, stream>>>(Ws1, Ws2, W1T, W2T);

    const unsigned short* xin = x0bf;
    unsigned short* bufs[2] = {xA, xB};
    for (int l = 0; l < NL; l++) {
        agg_kernel<<<NN / 16, 256, 0, stream>>>(xin, rowptr, col, hpre);
        unsigned short* xout = bufs[l & 1];
        mlp_kernel<<<(NN + 63) / 64, 256, 0, stream>>>(hpre, W1T + l * DD * DD, bs1 + l * DD,
                                                       W2T + l * DD * DD, bs2 + l * DD, xout);
        xin = xout;
    }
    pool_kernel<<<NG, 128, 0, stream>>>(xin, batch, out);
}

// Round 8
// 533.042 us; speedup vs baseline: 1.0958x; 1.0958x over previous
//
#include <hip/hip_runtime.h>

#define NN 50000
#define NE 1600000
#define DD 128
#define NL 4
#define NG 512
#define NBUK 196    // dst buckets of 256 nodes: ceil(50000/256)
#define NBLK 196    // edge blocks: ceil(NE/8192)
#define EPB 8192    // edges per block in bucket passes
#define HN (NBUK * NBLK)  // 38416
#define HT 151      // ceil(HN/256)

typedef __attribute__((ext_vector_type(8))) short short8;
typedef __attribute__((ext_vector_type(4))) float floatx4;

__device__ __forceinline__ unsigned short f2bf(float f) {
    unsigned int u = __float_as_uint(f);
    u += 0x7fffu + ((u >> 16) & 1u);
    return (unsigned short)(u >> 16);
}
__device__ __forceinline__ float bf2f(unsigned short u) {
    return __uint_as_float(((unsigned int)u) << 16);
}

// ---------- fp32 -> bf16 convert (layer-0 input) ----------
__global__ __launch_bounds__(256) void cvt_kernel(const float* __restrict__ x,
                                                  unsigned short* __restrict__ xbf) {
    int idx = blockIdx.x * 256 + threadIdx.x;  // one float4 per thread
    float4 f = ((const float4*)x)[idx];
    ushort4 o;
    o.x = f2bf(f.x); o.y = f2bf(f.y); o.z = f2bf(f.z); o.w = f2bf(f.w);
    ((ushort4*)xbf)[idx] = o;
}

// ---------- CSR build: LDS-only counting sort (ZERO global atomics) ----------
// R6/R7 counters proved global atomic RMWs execute memory-side on gfx950
// (~35 B write-through + serialized round trip each, scope hints ignored):
// 1.6M atomics = 56 MB WRITE_SIZE and 66 us. So: bucket sort with LDS atomics.

// Pass 1: per-(block, bucket) histogram, bucket = dst>>8
__global__ __launch_bounds__(512) void bhist_kernel(const int* __restrict__ dst,
                                                    int* __restrict__ hist) {
    __shared__ int h[NBUK];
    int tid = threadIdx.x;
    for (int i = tid; i < NBUK; i += 512) h[i] = 0;
    __syncthreads();
    int base = blockIdx.x * EPB;
#pragma unroll
    for (int it = 0; it < EPB / 512; it++) {
        int e = base + it * 512 + tid;
        if (e < NE) atomicAdd(&h[dst[e] >> 8], 1);
    }
    __syncthreads();
    for (int i = tid; i < NBUK; i += 512) hist[i * NBLK + blockIdx.x] = h[i];
}

// Pass 2a/2b/2c: exclusive scan of hist[HN] (bucket-major) -> bkoff[HN]
__global__ __launch_bounds__(256) void sum_tiles_kernel(const int* __restrict__ in,
                                                        int* __restrict__ tsum, int n) {
    int i = blockIdx.x * 256 + threadIdx.x;
    __shared__ int s[256];
    s[threadIdx.x] = (i < n) ? in[i] : 0;
    __syncthreads();
    for (int off = 128; off > 0; off >>= 1) {
        if (threadIdx.x < off) s[threadIdx.x] += s[threadIdx.x + off];
        __syncthreads();
    }
    if (threadIdx.x == 0) tsum[blockIdx.x] = s[0];
}

__global__ __launch_bounds__(256) void scan_tiles_kernel(const int* __restrict__ tsum,
                                                         int* __restrict__ toff, int ntiles) {
    int t = threadIdx.x;
    __shared__ int s[256];
    int v = (t < ntiles) ? tsum[t] : 0;
    s[t] = v;
    __syncthreads();
    for (int off = 1; off < 256; off <<= 1) {
        int u = (t >= off) ? s[t - off] : 0;
        __syncthreads();
        s[t] += u;
        __syncthreads();
    }
    if (t < ntiles) toff[t] = s[t] - v;
}

__global__ __launch_bounds__(256) void scan_out_kernel(const int* __restrict__ in,
                                                       const int* __restrict__ toff,
                                                       int* __restrict__ out, int n) {
    int i = blockIdx.x * 256 + threadIdx.x;
    int t = threadIdx.x;
    int v = (i < n) ? in[i] : 0;
    __shared__ int s[256];
    s[t] = v;
    __syncthreads();
    for (int off = 1; off < 256; off <<= 1) {
        int u = (t >= off) ? s[t - off] : 0;
        __syncthreads();
        s[t] += u;
        __syncthreads();
    }
    if (i < n) out[i] = toff[blockIdx.x] + s[t] - v;
}

// Pass 3: scatter edges into bucket-sorted ebuf. LDS atomics give the slot within
// the (block,bucket) segment — any order within a segment is valid.
__global__ __launch_bounds__(512) void bscatter_kernel(const int* __restrict__ src,
                                                       const int* __restrict__ dst,
                                                       const int* __restrict__ bkoff,
                                                       int2* __restrict__ ebuf) {
    __shared__ int h[NBUK];
    int tid = threadIdx.x;
    for (int i = tid; i < NBUK; i += 512) h[i] = 0;
    __syncthreads();
    int base = blockIdx.x * EPB;
#pragma unroll
    for (int it = 0; it < EPB / 512; it++) {
        int e = base + it * 512 + tid;
        if (e < NE) {
            int d = dst[e];
            int bu = d >> 8;
            int p = atomicAdd(&h[bu], 1);
            ebuf[bkoff[bu * NBLK + blockIdx.x] + p] = make_int2(src[e], d);
        }
    }
}

// Pass 4: one block per bucket (256 nodes): LDS histogram over dst&255 -> LDS scan
// -> rowptr for this bucket's nodes + scatter src into final CSR col.
__global__ __launch_bounds__(256) void bucket_csr_kernel(const int2* __restrict__ ebuf,
                                                         const int* __restrict__ bkoff,
                                                         int* __restrict__ rowptr,
                                                         int* __restrict__ col) {
    __shared__ int cnt[256], exc[256], c2[256];
    int b = blockIdx.x, tid = threadIdx.x;
    int segstart = bkoff[b * NBLK];
    int segend = (b < NBUK - 1) ? bkoff[(b + 1) * NBLK] : NE;
    cnt[tid] = 0;
    c2[tid] = 0;
    __syncthreads();
    for (int i = segstart + tid; i < segend; i += 256)
        atomicAdd(&cnt[ebuf[i].y & 255], 1);
    __syncthreads();
    int v = cnt[tid];
    exc[tid] = v;
    __syncthreads();
    for (int off = 1; off < 256; off <<= 1) {
        int u = (tid >= off) ? exc[tid - off] : 0;
        __syncthreads();
        exc[tid] += u;
        __syncthreads();
    }
    int excl = exc[tid] - v;  // exclusive prefix
    exc[tid] = excl;          // own-slot rewrite; others read only after barrier
    int node = (b << 8) + tid;
    if (node <= NN) rowptr[node] = segstart + excl;
    __syncthreads();
    for (int i = segstart + tid; i < segend; i += 256) {
        int2 ev = ebuf[i];
        int low = ev.y & 255;
        int p = atomicAdd(&c2[low], 1);
        col[segstart + exc[low] + p] = ev.x;
    }
}

// ---------- weight prep: fp32 [l][k][n] -> bf16 transposed [l][n][k] ----------
__global__ __launch_bounds__(256) void prep_kernel(const float* __restrict__ Ws1,
                                                   const float* __restrict__ Ws2,
                                                   unsigned short* __restrict__ W1T,
                                                   unsigned short* __restrict__ W2T) {
    int idx = blockIdx.x * 256 + threadIdx.x;  // [0, NL*DD*DD)
    int l = idx >> 14;
    int rem = idx & 16383;
    int k = rem >> 7;
    int n = rem & 127;
    int o = (l << 14) + (n << 7) + k;
    W1T[o] = f2bf(Ws1[idx]);
    W2T[o] = f2bf(Ws2[idx]);
}

// ---------- aggregation: hpre[i] = x[i] + sum_{j in N(i)} x[j], bf16 in/out ----------
// Standalone (NOT fused with MLP — R5: fusing cost 2.4x fetch rate via occupancy).
// 16 lanes/node, uint4 (8 bf16) per lane; fp32 accum; x8 edge unroll.
__global__ __launch_bounds__(256) void agg_kernel(const unsigned short* __restrict__ xbf,
                                                  const int* __restrict__ rowptr,
                                                  const int* __restrict__ col,
                                                  unsigned short* __restrict__ hpre) {
    int g = threadIdx.x >> 4;   // 16 node-groups per block
    int lane = threadIdx.x & 15;
    int node = blockIdx.x * 16 + g;  // NN = 3125*16 exactly
    const uint4* base = (const uint4*)xbf;
    float a[8];
    {
        uint4 v = base[node * 16 + lane];
        a[0] = __uint_as_float(v.x << 16); a[1] = __uint_as_float(v.x & 0xFFFF0000u);
        a[2] = __uint_as_float(v.y << 16); a[3] = __uint_as_float(v.y & 0xFFFF0000u);
        a[4] = __uint_as_float(v.z << 16); a[5] = __uint_as_float(v.z & 0xFFFF0000u);
        a[6] = __uint_as_float(v.w << 16); a[7] = __uint_as_float(v.w & 0xFFFF0000u);
    }
    int s = rowptr[node], e = rowptr[node + 1];
    int i = s;
    for (; i + 8 <= e; i += 8) {
        uint4 v0 = base[col[i] * 16 + lane];
        uint4 v1 = base[col[i + 1] * 16 + lane];
        uint4 v2 = base[col[i + 2] * 16 + lane];
        uint4 v3 = base[col[i + 3] * 16 + lane];
        uint4 v4 = base[col[i + 4] * 16 + lane];
        uint4 v5 = base[col[i + 5] * 16 + lane];
        uint4 v6 = base[col[i + 6] * 16 + lane];
        uint4 v7 = base[col[i + 7] * 16 + lane];
#define ACC(V)                                                            \
        a[0] += __uint_as_float(V.x << 16); a[1] += __uint_as_float(V.x & 0xFFFF0000u); \
        a[2] += __uint_as_float(V.y << 16); a[3] += __uint_as_float(V.y & 0xFFFF0000u); \
        a[4] += __uint_as_float(V.z << 16); a[5] += __uint_as_float(V.z & 0xFFFF0000u); \
        a[6] += __uint_as_float(V.w << 16); a[7] += __uint_as_float(V.w & 0xFFFF0000u)
        ACC(v0); ACC(v1); ACC(v2); ACC(v3); ACC(v4); ACC(v5); ACC(v6); ACC(v7);
    }
    for (; i < e; i++) {
        uint4 v = base[col[i] * 16 + lane];
        ACC(v);
    }
#undef ACC
    uint4 o;
    o.x = (unsigned int)f2bf(a[0]) | ((unsigned int)f2bf(a[1]) << 16);
    o.y = (unsigned int)f2bf(a[2]) | ((unsigned int)f2bf(a[3]) << 16);
    o.z = (unsigned int)f2bf(a[4]) | ((unsigned int)f2bf(a[5]) << 16);
    o.w = (unsigned int)f2bf(a[6]) | ((unsigned int)f2bf(a[7]) << 16);
    ((uint4*)hpre)[node * 16 + lane] = o;
}

// ---------- fused MLP: out = relu(A@W1+b1)@W2 + b2 (bf16 in/out, fp32 accum) ----------
// 64 rows/block, 4 waves, wave w owns rows [16w,16w+16); 8 n-tiles per wave.
__global__ __launch_bounds__(256) void mlp_kernel(const unsigned short* __restrict__ A,
                                                  const unsigned short* __restrict__ W1T,
                                                  const float* __restrict__ b1,
                                                  const unsigned short* __restrict__ W2T,
                                                  const float* __restrict__ b2,
                                                  unsigned short* __restrict__ out) {
    __shared__ unsigned short Hs[64][136];  // +8 pad
    int tid = threadIdx.x;
    int w = tid >> 6;
    int lane = tid & 63;
    int quad = lane >> 4;
    int li = lane & 15;
    int row0 = blockIdx.x * 64;
    int arow = row0 + 16 * w + li;
    bool avalid = arow < NN;
    const unsigned short* arp = A + (size_t)arow * DD;

    floatx4 acc[8];
#pragma unroll
    for (int tn = 0; tn < 8; tn++) acc[tn] = (floatx4){0.f, 0.f, 0.f, 0.f};

#pragma unroll
    for (int kk = 0; kk < 4; kk++) {
        int k0 = kk * 32 + quad * 8;
        short8 af = avalid ? *(const short8*)(arp + k0)
                           : (short8){0, 0, 0, 0, 0, 0, 0, 0};
#pragma unroll
        for (int tn = 0; tn < 8; tn++) {
            short8 bf = *(const short8*)(W1T + ((tn * 16 + li) << 7) + k0);
            acc[tn] = __builtin_amdgcn_mfma_f32_16x16x32_bf16(af, bf, acc[tn], 0, 0, 0);
        }
    }
    // epilogue A: relu(acc + b1) -> Hs (bf16, row-major for stage-B A-fragments)
#pragma unroll
    for (int tn = 0; tn < 8; tn++) {
        float bias = b1[tn * 16 + li];
#pragma unroll
        for (int r = 0; r < 4; r++) {
            float v = acc[tn][r] + bias;
            v = fmaxf(v, 0.f);
            Hs[16 * w + quad * 4 + r][tn * 16 + li] = f2bf(v);
        }
    }
    __syncthreads();

#pragma unroll
    for (int tn = 0; tn < 8; tn++) acc[tn] = (floatx4){0.f, 0.f, 0.f, 0.f};
#pragma unroll
    for (int kk = 0; kk < 4; kk++) {
        int k0 = kk * 32 + quad * 8;
        short8 af = *(const short8*)&Hs[16 * w + li][k0];
#pragma unroll
        for (int tn = 0; tn < 8; tn++) {
            short8 bf = *(const short8*)(W2T + ((tn * 16 + li) << 7) + k0);
            acc[tn] = __builtin_amdgcn_mfma_f32_16x16x32_bf16(af, bf, acc[tn], 0, 0, 0);
        }
    }
#pragma unroll
    for (int tn = 0; tn < 8; tn++) {
        float bias = b2[tn * 16 + li];
#pragma unroll
        for (int r = 0; r < 4; r++) {
            int grow = row0 + 16 * w + quad * 4 + r;
            if (grow < NN) out[(size_t)grow * DD + tn * 16 + li] = f2bf(acc[tn][r] + bias);
        }
    }
}

// ---------- global add pool: batch sorted -> per-graph contiguous range ----------
__global__ __launch_bounds__(128) void pool_kernel(const unsigned short* __restrict__ x,
                                                   const int* __restrict__ batch,
                                                   float* __restrict__ out) {
    int g = blockIdx.x;
    int lo = 0, hi = NN;
    while (lo < hi) { int mid = (lo + hi) >> 1; if (batch[mid] < g) lo = mid + 1; else hi = mid; }
    int s = lo;
    hi = NN;
    while (lo < hi) { int mid = (lo + hi) >> 1; if (batch[mid] < g + 1) lo = mid + 1; else hi = mid; }
    int e = lo;
    int d = threadIdx.x;
    float acc = 0.f;
    for (int i = s; i < e; i++) acc += bf2f(x[(size_t)i * DD + d]);
    out[g * DD + d] = acc;
}

extern "C" void kernel_launch(void* const* d_in, const int* in_sizes, int n_in,
                              void* d_out, int out_size, void* d_ws, size_t ws_size,
                              hipStream_t stream) {
    const float* x0 = (const float*)d_in[0];
    const int* edge = (const int*)d_in[1];
    const int* batch = (const int*)d_in[2];
    const float* Ws1 = (const float*)d_in[3];
    const float* bs1 = (const float*)d_in[4];
    const float* Ws2 = (const float*)d_in[5];
    const float* bs2 = (const float*)d_in[6];
    float* out = (float*)d_out;
    const int* src = edge;
    const int* dst = edge + NE;

    char* ws = (char*)d_ws;
    size_t off = 0;
    auto alloc = [&](size_t bytes) {
        void* p = ws + off;
        off += (bytes + 255) & ~(size_t)255;
        return p;
    };
    unsigned short* x0bf = (unsigned short*)alloc((size_t)NN * DD * 2);
    unsigned short* xA = (unsigned short*)alloc((size_t)NN * DD * 2);
    unsigned short* xB = (unsigned short*)alloc((size_t)NN * DD * 2);
    unsigned short* hpre = (unsigned short*)alloc((size_t)NN * DD * 2);
    int* col = (int*)alloc((size_t)NE * 4);
    int2* ebuf = (int2*)alloc((size_t)NE * 8);
    int* hist = (int*)alloc((size_t)HN * 4);
    int* bkoff = (int*)alloc((size_t)HN * 4);
    int* tsum = (int*)alloc((size_t)HT * 4);
    int* toff = (int*)alloc((size_t)HT * 4);
    int* rowptr = (int*)alloc((size_t)(NN + 1) * 4);
    unsigned short* W1T = (unsigned short*)alloc((size_t)NL * DD * DD * 2);
    unsigned short* W2T = (unsigned short*)alloc((size_t)NL * DD * DD * 2);

    cvt_kernel<<<(NN * DD / 4) / 256, 256, 0, stream>>>(x0, x0bf);
    bhist_kernel<<<NBLK, 512, 0, stream>>>(dst, hist);
    sum_tiles_kernel<<<HT, 256, 0, stream>>>(hist, tsum, HN);
    scan_tiles_kernel<<<1, 256, 0, stream>>>(tsum, toff, HT);
    scan_out_kernel<<<HT, 256, 0, stream>>>(hist, toff, bkoff, HN);
    bscatter_kernel<<<NBLK, 512, 0, stream>>>(src, dst, bkoff, ebuf);
    bucket_csr_kernel<<<NBUK, 256, 0, stream>>>(ebuf, bkoff, rowptr, col);
    prep_kernel<<<(NL * DD * DD) / 256, 256, 0, stream>>>(Ws1, Ws2, W1T, W2T);

    const unsigned short* xin = x0bf;
    unsigned short* bufs[2] = {xA, xB};
    for (int l = 0; l < NL; l++) {
        agg_kernel<<<NN / 16, 256, 0, stream>>>(xin, rowptr, col, hpre);
        unsigned short* xout = bufs[l & 1];
        mlp_kernel<<<(NN + 63) / 64, 256, 0, stream>>>(hpre, W1T + l * DD * DD, bs1 + l * DD,
                                                       W2T + l * DD * DD, bs2 + l * DD, xout);
        xin = xout;
    }
    pool_kernel<<<NG, 128, 0, stream>>>(xin, batch, out);
}